// Round 9
// baseline (243.640 us; speedup 1.0000x reference)
//
#include <hip/hip_runtime.h>

// ---------- types ----------
typedef _Float16 f16;
typedef _Float16 f16x4 __attribute__((ext_vector_type(4)));
typedef _Float16 f16x8 __attribute__((ext_vector_type(8)));
typedef float    f32x4 __attribute__((ext_vector_type(4)));

#define N_ROWS 100000
#define RT 782            // 782 * 128 = 100096 padded rows
#define LSH1 136
#define LSH2 72

// ws: weights only
#define W1T_OFF 0
#define W1T_BYTES (256 * 256 * 2)
#define W2T_OFF W1T_BYTES

// arena (bytes): X dbuf (8K each) | W dbuf (16K each); h1s/h2s overlay after K-loop
#define XS0 0
#define XS1 8192
#define WS0 16384
#define WS1 32768
#define ARENA 53248
#define H1S 0             // 128*136*2 = 34816
#define H2S 34816         // 128*72*2  = 18432 -> 53248

// ---------- prep: combined, transposed f16 weights ----------
__global__ void prep_w(const float* __restrict__ wz1, const float* __restrict__ wh1,
                       const float* __restrict__ wz2, const float* __restrict__ wh2,
                       f16* __restrict__ W1T, f16* __restrict__ W2T) {
    const int b = blockIdx.x;
    if (b < 256) {
        int idx = b * 256 + threadIdx.x;
        int k = idx >> 8, c = idx & 255;
        const float* w = (c < 128) ? wz1 : wh1;
        int cc = c & 127;
        W1T[c * 256 + k] = (f16)(w[k * 128 + cc] + w[384 * 128 + k * 128 + cc]);
    } else {
        int idx = (b - 256) * 256 + threadIdx.x;
        int k = idx >> 7, c = idx & 127;
        const float* w = (c < 64) ? wz2 : wh2;
        int cc = c & 63;
        W2T[c * 128 + k] = (f16)(w[k * 64 + cc] + w[192 * 64 + k * 64 + cc]);
    }
}

// ---------- fused: 128 rows/block, 512 thr, dbuf K-loop, xor-swizzled LDS ----------
__global__ __launch_bounds__(512, 4) void fused(
    const float* __restrict__ x,
    const f16* __restrict__ W1T, const f16* __restrict__ W2T,
    const float* __restrict__ bz1, const float* __restrict__ bh1,
    const float* __restrict__ bz2, const float* __restrict__ bh2,
    const float* __restrict__ wl1, const float* __restrict__ bl1,
    const float* __restrict__ wl2, const float* __restrict__ bl2,
    float* __restrict__ out)
{
    __shared__ __align__(16) char arena[ARENA];
    const int tid = threadIdx.x, lane = tid & 63, wave = tid >> 6;
    const int ln = lane & 15, quad = lane >> 4;
    const int ch = wave >> 1, rh2 = wave & 1;      // col-quarter, row-half
    const int r0 = blockIdx.x * 128;

    // ---- staging maps ----
    // X: thread t -> row xr=t>>2, slot g=t&3; slot g holds global f32 group g^sx, sx=(xr>>2)&3
    const int xr = tid >> 2, xg = tid & 3;
    const int sx = (xr >> 2) & 3;
    int gxr = r0 + xr; if (gxr >= N_ROWS) gxr = N_ROWS - 1;
    const float* xp = x + (size_t)gxr * 256 + 8 * (xg ^ sx);
    // W: thread t -> col wc=t&255, pair p=t>>8; stages slots {2p,2p+1}, slot s holds group s^sw
    const int wcl = tid & 255, wp2 = tid >> 8;
    const int sw = (wcl >> 1) & 3;
    const f16* wp = W1T + (size_t)wcl * 256;
    const int wq0 = (2 * wp2) ^ sw, wq1 = (2 * wp2 + 1) ^ sw;

    // K-loop read bases (per-lane constants)
    // X frag (row, quad, kc): f16 idx row*32 + 8*(quad^((row>>2)&3)) in buf kc... rounds indexed
    // W frag (col=16M+ln, quad): f16 idx col*32 + 8*(quad^((ln>>1)&3))
    const int swr = (ln >> 1) & 3;

    f32x4 acc[4][4];                               // [mi][nt]
#pragma unroll
    for (int a = 0; a < 4; ++a)
#pragma unroll
        for (int b = 0; b < 4; ++b) acc[a][b] = (f32x4){0.f, 0.f, 0.f, 0.f};

    float4 pxa, pxb; f16x8 pw0, pw1;
#define PRE(R) { pxa = *(const float4*)(xp + (R) * 32);  pxb = *(const float4*)(xp + (R) * 32 + 4); \
                 pw0 = *(const f16x8*)(wp + (R) * 32 + 8 * wq0); \
                 pw1 = *(const f16x8*)(wp + (R) * 32 + 8 * wq1); }

    PRE(0)

#pragma unroll
    for (int it = 0; it < 8; ++it) {
        f16* XsB = (f16*)(arena + ((it & 1) ? XS1 : XS0));
        f16* WsB = (f16*)(arena + ((it & 1) ? WS1 : WS0));
        // commit (consumes prefetch -> nothing in flight at the barrier)
        *(f16x8*)&XsB[xr * 32 + 8 * xg] =
            (f16x8){(f16)pxa.x,(f16)pxa.y,(f16)pxa.z,(f16)pxa.w,
                    (f16)pxb.x,(f16)pxb.y,(f16)pxb.z,(f16)pxb.w};
        *(f16x8*)&WsB[wcl * 32 + 8 * (2 * wp2)]     = pw0;
        *(f16x8*)&WsB[wcl * 32 + 8 * (2 * wp2 + 1)] = pw1;
        __syncthreads();
        if (it < 7) { PRE(it + 1) }
        __builtin_amdgcn_sched_barrier(0);         // pin prefetch issue here

        f16x8 bf[4], af[4];
#pragma unroll
        for (int nt = 0; nt < 4; ++nt) {
            const int row = 64 * rh2 + 16 * nt + ln;
            bf[nt] = *(const f16x8*)&XsB[row * 32 + 8 * (quad ^ ((row >> 2) & 3))];
        }
#pragma unroll
        for (int mi = 0; mi < 4; ++mi) {
            const int M = (mi < 2) ? (2 * ch + mi) : (8 + 2 * ch + mi - 2);
            af[mi] = *(const f16x8*)&WsB[(M * 16 + ln) * 32 + 8 * (quad ^ swr)];
        }
#pragma unroll
        for (int mi = 0; mi < 4; ++mi)
#pragma unroll
            for (int nt = 0; nt < 4; ++nt)
                acc[mi][nt] = __builtin_amdgcn_mfma_f32_16x16x32_f16(af[mi], bf[nt], acc[mi][nt], 0, 0, 0);
    }
#undef PRE
    __syncthreads();                               // K-loop done; arena reused

    // W2 frags prefetch (fly during epilogue): wave (ch) -> z col-tile ch, h col-tile ch+4
    f16x8 w2f[2][4];
#pragma unroll
    for (int kc = 0; kc < 4; ++kc) {
        w2f[0][kc] = *(const f16x8*)(W2T + (size_t)(16 * ch + ln) * 128 + kc * 32 + quad * 8);
        w2f[1][kc] = *(const f16x8*)(W2T + (size_t)(64 + 16 * ch + ln) * 128 + kc * 32 + quad * 8);
    }

    // P1 epilogue: gates -> h1s. D: col(ln)=X row, row(4quad+i)=W col.
    f16* h1s = (f16*)(arena + H1S);
#pragma unroll
    for (int mi = 0; mi < 2; ++mi) {
        const int jg0 = 32 * ch + 16 * mi + (quad << 2);
        const float4 zb = *(const float4*)(bz1 + jg0);
        const float4 hb = *(const float4*)(bh1 + jg0);
#pragma unroll
        for (int nt = 0; nt < 4; ++nt) {
            const int row = 64 * rh2 + 16 * nt + ln;
            f16x4 pk;
#pragma unroll
            for (int i = 0; i < 4; ++i) {
                float zp = acc[mi][nt][i]     + (&zb.x)[i];
                float hp = acc[mi + 2][nt][i] + (&hb.x)[i];
                float ex = __expf(2.0f * hp);
                float th = 1.0f - 2.0f / (ex + 1.0f);      // tanh
                float sg = 1.0f / (1.0f + __expf(zp));     // 1 - sigmoid
                pk[i] = (f16)fmaxf(th * sg, 0.0f);
            }
            *(f16x4*)&h1s[row * LSH1 + jg0] = pk;
        }
    }
    __syncthreads();

    // ---- P2: h2 = gates(h1 @ W2); wave (ch,rh2): z-tile ch, h-tile ch+4, rows 64*rh2.. ----
    f32x4 acc2[2][4];
#pragma unroll
    for (int a = 0; a < 2; ++a)
#pragma unroll
        for (int b = 0; b < 4; ++b) acc2[a][b] = (f32x4){0.f, 0.f, 0.f, 0.f};
#pragma unroll
    for (int kc = 0; kc < 4; ++kc) {
        f16x8 bf[4];
#pragma unroll
        for (int nt = 0; nt < 4; ++nt)
            bf[nt] = *(const f16x8*)&h1s[(64 * rh2 + 16 * nt + ln) * LSH1 + kc * 32 + quad * 8];
#pragma unroll
        for (int m = 0; m < 2; ++m)
#pragma unroll
            for (int nt = 0; nt < 4; ++nt)
                acc2[m][nt] = __builtin_amdgcn_mfma_f32_16x16x32_f16(w2f[m][kc], bf[nt], acc2[m][nt], 0, 0, 0);
    }

    f16* h2s = (f16*)(arena + H2S);                // disjoint from h1s -> no barrier needed
    {
        const int jg0 = 16 * ch + (quad << 2);
        const float4 zb = *(const float4*)(bz2 + jg0);
        const float4 hb = *(const float4*)(bh2 + jg0);
#pragma unroll
        for (int nt = 0; nt < 4; ++nt) {
            const int row = 64 * rh2 + 16 * nt + ln;
            f16x4 pk;
#pragma unroll
            for (int i = 0; i < 4; ++i) {
                float zp = acc2[0][nt][i] + (&zb.x)[i];
                float hp = acc2[1][nt][i] + (&hb.x)[i];
                float ex = __expf(2.0f * hp);
                float th = 1.0f - 2.0f / (ex + 1.0f);
                float sg = 1.0f / (1.0f + __expf(zp));
                pk[i] = (f16)fmaxf(th * sg, 0.0f);
            }
            *(f16x4*)&h2s[row * LSH2 + jg0] = pk;
        }
    }
    __syncthreads();

    // ---- P3: out = relu(h2 @ wl1 + bl1) @ wl2 + bl2; wave w -> rows 16w..16w+15 ----
    const float blv = bl1[ln], wlv = wl2[ln], bl2v = bl2[0];
    f16x8 bfr[2];
#pragma unroll
    for (int kc = 0; kc < 2; ++kc)
#pragma unroll
        for (int j = 0; j < 8; ++j)
            bfr[kc][j] = (f16)wl1[(32 * kc + 8 * quad + j) * 16 + ln];

    f32x4 acc3 = (f32x4){0.f, 0.f, 0.f, 0.f};
#pragma unroll
    for (int kc = 0; kc < 2; ++kc) {
        f16x8 af = *(const f16x8*)&h2s[(16 * wave + ln) * LSH2 + kc * 32 + quad * 8];
        acc3 = __builtin_amdgcn_mfma_f32_16x16x32_f16(af, bfr[kc], acc3, 0, 0, 0);
    }
#pragma unroll
    for (int i = 0; i < 4; ++i) {
        float v = fmaxf(acc3[i] + blv, 0.0f) * wlv;
        v += __shfl_xor(v, 1);
        v += __shfl_xor(v, 2);
        v += __shfl_xor(v, 4);
        v += __shfl_xor(v, 8);
        if (ln == 0) {
            const int row = r0 + 16 * wave + (quad << 2) + i;
            if (row < N_ROWS) out[row] = v + bl2v;
        }
    }
}

// ---------- launch ----------
extern "C" void kernel_launch(void* const* d_in, const int* in_sizes, int n_in,
                              void* d_out, int out_size, void* d_ws, size_t ws_size,
                              hipStream_t stream) {
    const float* x   = (const float*)d_in[0];
    const float* wz1 = (const float*)d_in[3];
    const float* bz1 = (const float*)d_in[4];
    const float* wh1 = (const float*)d_in[7];
    const float* bh1 = (const float*)d_in[8];
    const float* wz2 = (const float*)d_in[9];
    const float* bz2 = (const float*)d_in[10];
    const float* wh2 = (const float*)d_in[13];
    const float* bh2 = (const float*)d_in[14];
    const float* wl1 = (const float*)d_in[15];
    const float* bl1 = (const float*)d_in[16];
    const float* wl2 = (const float*)d_in[17];
    const float* bl2 = (const float*)d_in[18];

    char* ws = (char*)d_ws;
    f16* W1T = (f16*)(ws + W1T_OFF);
    f16* W2T = (f16*)(ws + W2T_OFF);
    float* out = (float*)d_out;

    prep_w<<<320, 256, 0, stream>>>(wz1, wh1, wz2, wh2, W1T, W2T);
    fused<<<RT, 512, 0, stream>>>(x, W1T, W2T, bz1, bh1, bz2, bh2,
                                  wl1, bl1, wl2, bl2, out);
}